// Round 10
// baseline (278.850 us; speedup 1.0000x reference)
//
#include <hip/hip_runtime.h>

#define BATCH 16
#define CIN 512
#define NPIX 4096

typedef __attribute__((ext_vector_type(8))) short bf16x8;
typedef __attribute__((ext_vector_type(4))) float f32x4;

#define MFMA(a,b,c) __builtin_amdgcn_mfma_f32_16x16x32_bf16((a),(b),(c),0,0,0)

// async global->LDS DMA, 16B/lane, dst = uniform base + lane*16
#define GLOAD(g, l) __builtin_amdgcn_global_load_lds( \
    (const __attribute__((address_space(1))) unsigned int*)(g), \
    (__attribute__((address_space(3))) unsigned int*)(l), 16, 0, 0)

union PK  { short s[8]; bf16x8 v; };
union PK4 { short s[4]; uint2 u; };

__device__ __forceinline__ unsigned short bf16_rne(float f){
  unsigned u = __float_as_uint(f);
  return (unsigned short)((u + 0x7fffu + ((u >> 16) & 1u)) >> 16);
}
__device__ __forceinline__ void f32_split(float f, short &h, short &l){
  unsigned short hu = bf16_rne(f);
  h = (short)hu;
  float fh = __uint_as_float((unsigned)hu << 16);
  l = (short)bf16_rne(f - fh);
}
__device__ __forceinline__ void split8(float4 a, float4 b, bf16x8 &h, bf16x8 &l){
  float vv[8] = {a.x,a.y,a.z,a.w,b.x,b.y,b.z,b.w};
  PK ph, pl;
  #pragma unroll
  for (int z=0;z<8;z++){ short hh,ll; f32_split(vv[z],hh,ll); ph.s[z]=hh; pl.s[z]=ll; }
  h = ph.v; l = pl.v;
}

// chunk-XOR swizzle within a 512-short row: (row,k) -> row*512 + slot*8 + (k&7)
__device__ __forceinline__ int offBig(int row, int k){
  int s = k >> 3;
  s = (s & ~7) | ((s ^ row) & 7);
  return row*512 + s*8 + (k & 7);
}

// ---------------- weight convert ----------------
// WALL [16 kt][640 rows][32 k] bf16, K-step-major, chunk^row&3 swizzle baked in.
//   rows 0-511: interleaved gate (2o=Wq[o], 2o+1=Wk[o]); 512-575: Ws hi; 576-639: We hi.
// WLOT [16 kt][64 rows][32 k]: Ws lo, same swizzle.
__global__ __launch_bounds__(256)
void k_convw(const float* __restrict__ Wq, const float* __restrict__ bq,
             const float* __restrict__ Wk, const float* __restrict__ bk,
             const float* __restrict__ Ws, const float* __restrict__ bs,
             const float* __restrict__ We, const float* __restrict__ be,
             short* __restrict__ WALL, short* __restrict__ WLOT,
             float* __restrict__ BG, float* __restrict__ BSE){
  int t = blockIdx.x*256 + threadIdx.x;   // t < 640*512
  if (t < 640*512){
    int r = t >> 9, k = t & 511;
    float v = (r < 512) ? ((r & 1) ? Wk[(r>>1)*512 + k] : Wq[(r>>1)*512 + k])
            : (r < 576) ? Ws[(r-512)*512 + k] : We[(r-576)*512 + k];
    short h, l; f32_split(v, h, l);
    int kt = k >> 5, lc = (k >> 3) & 3, e = k & 7;
    int pc = lc ^ (r & 3);
    WALL[((size_t)kt*640 + r)*32 + pc*8 + e] = h;
    if (r >= 512 && r < 576){
      int rlo = r - 512;
      WLOT[((size_t)kt*64 + rlo)*32 + (lc ^ (rlo & 3))*8 + e] = l;
    }
  }
  if (t < 512) BG[t] = (t & 1) ? bk[t>>1] : bq[t>>1];
  if (t < 128) BSE[t] = (t < 64) ? bs[t] : be[t-64];
}

// ---------------- fused front: gate + Qs(split,gate-folded) + Ke ----------------
// m97 anatomy: weights DMA'd per K-step via global_load_lds into dbuf A-tile
// (issued right after the barrier -> flies under MFMA); x^T staged once in XS.
// 8 waves x 5 row-fragments cover 640 rows; waves 6/7 add the Qs-lo MFMA.
// grid (64 nt, 16 b), 512 thr. LDS ~154 KB -> 1 block/CU, 2 waves/SIMD, regs<=256.
__global__ __launch_bounds__(512, 2)
void k_front(const float* __restrict__ x, const short* __restrict__ WALL,
             const short* __restrict__ WLOT, const float* __restrict__ BG,
             const float* __restrict__ BSE,
             float* __restrict__ QSG, short* __restrict__ KET, float* __restrict__ S){
  __shared__ __align__(16) short AB[2][640*32];   // 2 x 40 KB
  __shared__ __align__(16) short LO[2][64*32];    // 2 x 4 KB
  __shared__ __align__(16) short XS[64*512];      // 64 KB, [n][c] swizzled
  __shared__ float QKf[512];
  __shared__ float GF[64];
  int nt = blockIdx.x, b = blockIdx.y;
  int n0 = nt*64;
  int tid = threadIdx.x, w = tid>>6, lane = tid&63;
  int lr = lane&15, lk = (lane>>4)<<3;
  int cg = lane>>4;                         // k-chunk 0..3

  // prologue: issue kt=0 weight DMA immediately (flies under XS staging)
  {
    const char* src = (const char*)WALL;
    #pragma unroll
    for (int i=0;i<5;i++){
      int slot = i*8 + w;
      GLOAD(src + slot*1024 + lane*16, ((char*)&AB[0][0]) + slot*1024);
    }
    if (w < 4)
      GLOAD((const char*)WLOT + w*1024 + lane*16, ((char*)&LO[0][0]) + w*1024);
  }

  // XS stage: thread = channel c; all 16 float4 loads in flight before LDS writes
  {
    const float* xp = x + ((size_t)b*CIN + tid)*NPIX + n0;
    float4 vv[16];
    #pragma unroll
    for (int i=0;i<16;i++) vv[i] = *(const float4*)(xp + i*4);
    #pragma unroll
    for (int i=0;i<16;i++){
      float f[4] = {vv[i].x, vv[i].y, vv[i].z, vv[i].w};
      #pragma unroll
      for (int u=0;u<4;u++)
        XS[offBig(i*4+u, tid)] = (short)bf16_rne(f[u]);
    }
  }

  f32x4 acc[5][4] = {};
  int rowBase = w*80;                       // 5 frags x 16 rows per wave

  for (int kt=0; kt<16; kt++){
    int cur = kt & 1;
    __syncthreads();                        // drains DMA for buf[cur] + syncs readers
    if (kt < 15){                           // issue next-step DMA now (async)
      const char* src = (const char*)WALL + (size_t)(kt+1)*40960;
      #pragma unroll
      for (int i=0;i<5;i++){
        int slot = i*8 + w;
        GLOAD(src + slot*1024 + lane*16, ((char*)&AB[cur^1][0]) + slot*1024);
      }
      if (w < 4)
        GLOAD((const char*)WLOT + (size_t)(kt+1)*4096 + w*1024 + lane*16,
              ((char*)&LO[cur^1][0]) + w*1024);
    }
    bf16x8 bb[4];
    #pragma unroll
    for (int j=0;j<4;j++)
      bb[j] = *(const bf16x8*)&XS[offBig(j*16+lr, kt*32+lk)];
    int swz = ((cg ^ (lr & 3)) << 3);
    #pragma unroll
    for (int r=0;r<5;r++){
      int rowL = rowBase + r*16 + lr;
      bf16x8 a = *(const bf16x8*)&AB[cur][rowL*32 + swz];
      #pragma unroll
      for (int j=0;j<4;j++) acc[r][j] = MFMA(a, bb[j], acc[r][j]);
      int F = w*5 + r;
      if (F >= 32 && F < 36){               // Qs rows: add lo term
        int rowLo = F*16 - 512 + lr;
        bf16x8 alo = *(const bf16x8*)&LO[cur][rowLo*32 + swz];
        #pragma unroll
        for (int j=0;j<4;j++) acc[r][j] = MFMA(alo, bb[j], acc[r][j]);
      }
    }
  }

  int rq = (lane>>4)<<2;
  // ---- gate pair-reduce over QK frags (F<32) ----
  {
    float p[4] = {0.f,0.f,0.f,0.f};
    #pragma unroll
    for (int r=0;r<5;r++){
      int F = w*5 + r;
      if (F < 32){
        f32x4 bg = *(const f32x4*)&BG[F*16 + rq];
        #pragma unroll
        for (int j=0;j<4;j++){
          f32x4 a4 = acc[r][j];
          p[j] += (a4[0]+bg[0])*(a4[1]+bg[1]) + (a4[2]+bg[2])*(a4[3]+bg[3]);
        }
      }
    }
    #pragma unroll
    for (int j=0;j<4;j++){ p[j] += __shfl_xor(p[j],16); p[j] += __shfl_xor(p[j],32); }
    if (lane < 16){
      #pragma unroll
      for (int j=0;j<4;j++) QKf[w*64 + j*16 + lane] = p[j];
    }
  }
  __syncthreads();
  if (tid < 64){
    float s = 0.f;
    #pragma unroll
    for (int ww=0;ww<8;ww++) s += QKf[ww*64 + tid];
    GF[tid] = 1.f/(1.f + __expf(-s*(1.f/256.f)));
  }
  __syncthreads();

  // ---- Qs (F 32-35) and Ke (F 36-39) epilogues ----
  #pragma unroll
  for (int r=0;r<5;r++){
    int F = w*5 + r;
    if (F >= 32 && F < 36){
      int row0 = F*16 - 512 + rq;
      f32x4 bs4 = *(const f32x4*)&BSE[row0];
      float srow[4] = {0.f,0.f,0.f,0.f};
      #pragma unroll
      for (int j=0;j<4;j++){
        int nl = j*16 + lr;
        float g = GF[nl];
        int n = n0 + nl;
        #pragma unroll
        for (int q=0;q<4;q++){
          float v = (acc[r][j][q] + bs4[q]) * g;
          QSG[((size_t)(b*64) + row0 + q)*NPIX + n] = v;
          srow[q] += v;
        }
      }
      #pragma unroll
      for (int q=0;q<4;q++){
        float v = srow[q];
        v += __shfl_xor(v,1); v += __shfl_xor(v,2);
        v += __shfl_xor(v,4); v += __shfl_xor(v,8);
        if (lr == 0) atomicAdd(&S[b*64 + row0 + q], v);
      }
    } else if (F >= 36){
      int d0 = F*16 - 576 + rq;
      f32x4 be4 = *(const f32x4*)&BSE[64 + d0];
      #pragma unroll
      for (int j=0;j<4;j++){
        int n = n0 + j*16 + lr;
        PK4 pk;
        #pragma unroll
        for (int q=0;q<4;q++) pk.s[q] = (short)bf16_rne(acc[r][j][q] + be4[q]);
        *(uint2*)&KET[((size_t)(b*NPIX) + n)*64 + d0] = pk.u;
      }
    }
  }
}

// ---------------- M[b][512][64] += x . QSG^T over n (reg-split, no LDS) ----------------
__global__ __launch_bounds__(512)
void k_M(const float* __restrict__ x, const float* __restrict__ QSG,
         float* __restrict__ M){
  int slab = blockIdx.x, b = blockIdx.y;   // 16 slabs x 256 n
  int tid = threadIdx.x, w = tid>>6, lane = tid&63;
  int lr = lane&15, lk8 = (lane>>4)<<3;
  f32x4 acc[4][4] = {};
  for (int kt=0; kt<8; kt++){
    int noff = slab*256 + kt*32 + lk8;
    bf16x8 bh[4], bl[4];
    #pragma unroll
    for (int j=0;j<4;j++){
      const float* qp = QSG + ((size_t)(b*64) + j*16 + lr)*NPIX + noff;
      split8(*(const float4*)qp, *(const float4*)(qp+4), bh[j], bl[j]);
    }
    #pragma unroll
    for (int r=0;r<4;r++){
      const float* xp = x + ((size_t)(b*CIN) + w*64 + r*16 + lr)*NPIX + noff;
      bf16x8 ah, al;
      split8(*(const float4*)xp, *(const float4*)(xp+4), ah, al);
      #pragma unroll
      for (int j=0;j<4;j++){
        acc[r][j] = MFMA(al, bh[j], acc[r][j]);
        acc[r][j] = MFMA(ah, bl[j], acc[r][j]);
        acc[r][j] = MFMA(ah, bh[j], acc[r][j]);
      }
    }
  }
  int rq = (lane>>4)<<2;
  #pragma unroll
  for (int r=0;r<4;r++)
    #pragma unroll
    for (int j=0;j<4;j++)
      #pragma unroll
      for (int q=0;q<4;q++)
        atomicAdd(&M[((size_t)(b*CIN) + w*64 + r*16 + rq + q)*64 + j*16 + lr], acc[r][j][q]);
}

// ---------------- energy = Wv(f32) . M + bv*S  (VALU, exact) ----------------
__global__ __launch_bounds__(256)
void k_energy(const float* __restrict__ Wv, const float* __restrict__ bv,
              const float* __restrict__ M, const float* __restrict__ S,
              float* __restrict__ EN){
  __shared__ __align__(16) float ML[128*68];
  int cch = blockIdx.x, b = blockIdx.y;
  int tid = threadIdx.x;
  int d4 = tid & 15, ci = tid >> 4;
  f32x4 acc[2] = {};
  for (int kt=0; kt<4; kt++){
    __syncthreads();
    for (int i = tid; i < 2048; i += 256){
      int k = i >> 4, c4 = (i & 15) * 4;
      *(float4*)&ML[k*68 + c4] = *(const float4*)&M[((size_t)(b*CIN) + kt*128 + k)*64 + c4];
    }
    __syncthreads();
    #pragma unroll
    for (int m=0;m<2;m++){
      int c = cch*32 + ci + 16*m;
      const float* wvp = Wv + (size_t)c*512 + kt*128;
      for (int k4=0;k4<32;k4++){
        float4 wv4 = *(const float4*)(wvp + k4*4);
        f32x4 m0 = *(const f32x4*)&ML[(k4*4+0)*68 + d4*4];
        f32x4 m1 = *(const f32x4*)&ML[(k4*4+1)*68 + d4*4];
        f32x4 m2 = *(const f32x4*)&ML[(k4*4+2)*68 + d4*4];
        f32x4 m3 = *(const f32x4*)&ML[(k4*4+3)*68 + d4*4];
        acc[m] += m0*wv4.x + m1*wv4.y + m2*wv4.z + m3*wv4.w;
      }
    }
  }
  f32x4 s4 = *(const f32x4*)&S[b*64 + d4*4];
  #pragma unroll
  for (int m=0;m<2;m++){
    int c = cch*32 + ci + 16*m;
    f32x4 r = acc[m] + s4*bv[c];
    *(f32x4*)&EN[((size_t)(b*CIN) + c)*64 + d4*4] = r;
  }
}

// ---------------- softmax over d=64 ----------------
__global__ __launch_bounds__(256)
void k_softmax(const float* __restrict__ EN, short* __restrict__ ATT){
  int row = blockIdx.x*4 + (threadIdx.x>>6);
  int lane = threadIdx.x & 63;
  float v = EN[(size_t)row*64 + lane];
  float m = v;
  #pragma unroll
  for (int s=1;s<64;s<<=1) m = fmaxf(m, __shfl_xor(m, s));
  float e = __expf(v - m);
  float sum = e;
  #pragma unroll
  for (int s=1;s<64;s<<=1) sum += __shfl_xor(sum, s);
  ATT[(size_t)row*64 + lane] = (short)bf16_rne(e / sum);
}

// ---------------- out = x + attn . Ke ----------------
__global__ __launch_bounds__(512)
void k_out(const float* __restrict__ x, const short* __restrict__ ATT,
           const short* __restrict__ KET, float* __restrict__ out){
  int nt = blockIdx.x, b = blockIdx.y;
  int n0 = nt*64;
  int tid = threadIdx.x, w = tid>>6, lane = tid&63;
  int lr = lane&15, lk = (lane>>4)<<3;
  f32x4 acc[4][4] = {};
  #pragma unroll
  for (int kt=0; kt<2; kt++){
    bf16x8 bb[4];
    #pragma unroll
    for (int j=0;j<4;j++)
      bb[j] = *(const bf16x8*)&KET[((size_t)(b*NPIX) + n0 + j*16 + lr)*64 + kt*32 + lk];
    #pragma unroll
    for (int r=0;r<4;r++){
      bf16x8 a = *(const bf16x8*)&ATT[((size_t)(b*CIN) + w*64 + r*16 + lr)*64 + kt*32 + lk];
      #pragma unroll
      for (int j=0;j<4;j++)
        acc[r][j] = MFMA(a, bb[j], acc[r][j]);
    }
  }
  int rq = (lane>>4)<<2;
  #pragma unroll
  for (int r=0;r<4;r++)
    #pragma unroll
    for (int j=0;j<4;j++){
      int col = n0 + j*16 + lr;
      #pragma unroll
      for (int q=0;q<4;q++){
        size_t idx = ((size_t)(b*CIN) + w*64 + r*16 + rq + q)*NPIX + col;
        out[idx] = x[idx] + acc[r][j][q];
      }
    }
}

extern "C" void kernel_launch(void* const* d_in, const int* in_sizes, int n_in,
                              void* d_out, int out_size, void* d_ws, size_t ws_size,
                              hipStream_t stream){
  const float* x   = (const float*)d_in[0];
  const float* Wq  = (const float*)d_in[1];
  const float* bq  = (const float*)d_in[2];
  const float* Wk  = (const float*)d_in[3];
  const float* bk  = (const float*)d_in[4];
  const float* Wv  = (const float*)d_in[5];
  const float* bv  = (const float*)d_in[6];
  const float* Wsq = (const float*)d_in[7];
  const float* bsq = (const float*)d_in[8];
  const float* We  = (const float*)d_in[9];
  const float* be  = (const float*)d_in[10];
  float* out = (float*)d_out;

  char* wsb = (char*)d_ws;
  size_t off = 0;
  auto alloc = [&](size_t bytes)->void*{
    void* p = wsb + off; off += (bytes + 255) & ~(size_t)255; return p;
  };
  short* WALL = (short*)alloc((size_t)640*512*2);
  short* WLOT = (short*)alloc((size_t)64*512*2);
  float* BG   = (float*)alloc(512*4);
  float* BSE  = (float*)alloc(128*4);
  float* QSG  = (float*)alloc((size_t)BATCH*64*NPIX*4);
  short* KET  = (short*)alloc((size_t)BATCH*NPIX*64*2);
  float* Mb   = (float*)alloc((size_t)BATCH*512*64*4);
  float* Sb   = (float*)alloc((size_t)BATCH*64*4);
  float* EN   = (float*)alloc((size_t)BATCH*512*64*4);
  short* ATT  = (short*)alloc((size_t)BATCH*512*64*2);

  hipMemsetAsync(Mb, 0, (size_t)BATCH*512*64*4, stream);
  hipMemsetAsync(Sb, 0, (size_t)BATCH*64*4, stream);

  k_convw  <<<1280, 256, 0, stream>>>(Wq,bq,Wk,bk,Wsq,bsq,We,be, WALL,WLOT,BG,BSE);
  k_front  <<<dim3(64,16), 512, 0, stream>>>(x, WALL, WLOT, BG, BSE, QSG, KET, Sb);
  k_M      <<<dim3(16,16), 512, 0, stream>>>(x, QSG, Mb);
  k_energy <<<dim3(16,16), 256, 0, stream>>>(Wv, bv, Mb, Sb, EN);
  k_softmax<<<2048, 256, 0, stream>>>(EN, ATT);
  k_out    <<<dim3(64,16), 512, 0, stream>>>(x, ATT, KET, out);
}

// Round 11
// 276.035 us; speedup vs baseline: 1.0102x; 1.0102x over previous
//
#include <hip/hip_runtime.h>

#define BATCH 16
#define CIN 512
#define NPIX 4096

typedef __attribute__((ext_vector_type(8))) short bf16x8;
typedef __attribute__((ext_vector_type(4))) float f32x4;

#define MFMA(a,b,c) __builtin_amdgcn_mfma_f32_16x16x32_bf16((a),(b),(c),0,0,0)

// async global->LDS DMA, 16B/lane, dst = uniform base + lane*16
#define GLOAD(g, l) __builtin_amdgcn_global_load_lds( \
    (const __attribute__((address_space(1))) unsigned int*)(g), \
    (__attribute__((address_space(3))) unsigned int*)(l), 16, 0, 0)

union PK  { short s[8]; bf16x8 v; };
union PK4 { short s[4]; uint2 u; };

__device__ __forceinline__ unsigned short bf16_rne(float f){
  unsigned u = __float_as_uint(f);
  return (unsigned short)((u + 0x7fffu + ((u >> 16) & 1u)) >> 16);
}
__device__ __forceinline__ void f32_split(float f, short &h, short &l){
  unsigned short hu = bf16_rne(f);
  h = (short)hu;
  float fh = __uint_as_float((unsigned)hu << 16);
  l = (short)bf16_rne(f - fh);
}
__device__ __forceinline__ void split8(float4 a, float4 b, bf16x8 &h, bf16x8 &l){
  float vv[8] = {a.x,a.y,a.z,a.w,b.x,b.y,b.z,b.w};
  PK ph, pl;
  #pragma unroll
  for (int z=0;z<8;z++){ short hh,ll; f32_split(vv[z],hh,ll); ph.s[z]=hh; pl.s[z]=ll; }
  h = ph.v; l = pl.v;
}

// chunk-XOR swizzle within a 512-short row: (row,k) -> row*512 + slot*8 + (k&7)
__device__ __forceinline__ int offBig(int row, int k){
  int s = k >> 3;
  s = (s & ~7) | ((s ^ row) & 7);
  return row*512 + s*8 + (k & 7);
}

// ---------------- weight convert ----------------
// WALL [16 kt][640 rows][32 k] bf16, K-step-major, chunk^row&3 swizzle baked in.
//   rows 0-511: interleaved gate (2o=Wq[o], 2o+1=Wk[o]); 512-575: Ws hi; 576-639: We hi.
// WLOT [16 kt][64 rows][32 k]: Ws lo, same swizzle.
__global__ __launch_bounds__(256)
void k_convw(const float* __restrict__ Wq, const float* __restrict__ bq,
             const float* __restrict__ Wk, const float* __restrict__ bk,
             const float* __restrict__ Ws, const float* __restrict__ bs,
             const float* __restrict__ We, const float* __restrict__ be,
             short* __restrict__ WALL, short* __restrict__ WLOT,
             float* __restrict__ BG, float* __restrict__ BSE){
  int t = blockIdx.x*256 + threadIdx.x;   // t < 640*512
  if (t < 640*512){
    int r = t >> 9, k = t & 511;
    float v = (r < 512) ? ((r & 1) ? Wk[(r>>1)*512 + k] : Wq[(r>>1)*512 + k])
            : (r < 576) ? Ws[(r-512)*512 + k] : We[(r-576)*512 + k];
    short h, l; f32_split(v, h, l);
    int kt = k >> 5, lc = (k >> 3) & 3, e = k & 7;
    int pc = lc ^ (r & 3);
    WALL[((size_t)kt*640 + r)*32 + pc*8 + e] = h;
    if (r >= 512 && r < 576){
      int rlo = r - 512;
      WLOT[((size_t)kt*64 + rlo)*32 + (lc ^ (rlo & 3))*8 + e] = l;
    }
  }
  if (t < 512) BG[t] = (t & 1) ? bk[t>>1] : bq[t>>1];
  if (t < 128) BSE[t] = (t < 64) ? bs[t] : be[t-64];
}

// ---------------- fused front: gate + Qs(split,gate-folded) + Ke ----------------
// R10 structure; SINGLE CHANGE: coalesced XS staging (4 lanes/channel-row,
// 64B contiguous per 4-lane group per instr, 1KB/wave/instr). The per-thread-
// own-row 16B-granule scatter was the common factor in all 140-215us fronts.
__global__ __launch_bounds__(512, 2)
void k_front(const float* __restrict__ x, const short* __restrict__ WALL,
             const short* __restrict__ WLOT, const float* __restrict__ BG,
             const float* __restrict__ BSE,
             float* __restrict__ QSG, short* __restrict__ KET, float* __restrict__ S){
  __shared__ __align__(16) short AB[2][640*32];   // 2 x 40 KB
  __shared__ __align__(16) short LO[2][64*32];    // 2 x 4 KB
  __shared__ __align__(16) short XS[64*512];      // 64 KB, [n][c] swizzled
  __shared__ float QKf[512];
  __shared__ float GF[64];
  int nt = blockIdx.x, b = blockIdx.y;
  int n0 = nt*64;
  int tid = threadIdx.x, w = tid>>6, lane = tid&63;
  int lr = lane&15, lk = (lane>>4)<<3;
  int cg = lane>>4;                         // k-chunk 0..3

  // prologue: issue kt=0 weight DMA immediately (flies under XS staging)
  {
    const char* src = (const char*)WALL;
    #pragma unroll
    for (int i=0;i<5;i++){
      int slot = i*8 + w;
      GLOAD(src + slot*1024 + lane*16, ((char*)&AB[0][0]) + slot*1024);
    }
    if (w < 4)
      GLOAD((const char*)WLOT + w*1024 + lane*16, ((char*)&LO[0][0]) + w*1024);
  }

  // XS stage, coalesced: 4 lanes per channel row, each reads float4 at
  // ni + u*16 (lanes 0-3 cover 64B contiguous per instruction).
  {
    int cc0 = tid >> 2;              // 0..127
    int ni  = (tid & 3) * 4;         // float offset in row
    #pragma unroll
    for (int p=0;p<4;p++){
      int cc = p*128 + cc0;
      const float* xp = x + ((size_t)b*CIN + cc)*NPIX + n0 + ni;
      float4 vv[4];
      #pragma unroll
      for (int u=0;u<4;u++) vv[u] = *(const float4*)(xp + u*16);
      #pragma unroll
      for (int u=0;u<4;u++){
        float f[4] = {vv[u].x, vv[u].y, vv[u].z, vv[u].w};
        #pragma unroll
        for (int z=0;z<4;z++)
          XS[offBig(ni + u*16 + z, cc)] = (short)bf16_rne(f[z]);
      }
    }
  }

  f32x4 acc[5][4] = {};
  int rowBase = w*80;                       // 5 frags x 16 rows per wave

  for (int kt=0; kt<16; kt++){
    int cur = kt & 1;
    __syncthreads();                        // drains DMA for buf[cur] + syncs readers
    if (kt < 15){                           // issue next-step DMA now (async)
      const char* src = (const char*)WALL + (size_t)(kt+1)*40960;
      #pragma unroll
      for (int i=0;i<5;i++){
        int slot = i*8 + w;
        GLOAD(src + slot*1024 + lane*16, ((char*)&AB[cur^1][0]) + slot*1024);
      }
      if (w < 4)
        GLOAD((const char*)WLOT + (size_t)(kt+1)*4096 + w*1024 + lane*16,
              ((char*)&LO[cur^1][0]) + w*1024);
    }
    bf16x8 bb[4];
    #pragma unroll
    for (int j=0;j<4;j++)
      bb[j] = *(const bf16x8*)&XS[offBig(j*16+lr, kt*32+lk)];
    int swz = ((cg ^ (lr & 3)) << 3);
    #pragma unroll
    for (int r=0;r<5;r++){
      int rowL = rowBase + r*16 + lr;
      bf16x8 a = *(const bf16x8*)&AB[cur][rowL*32 + swz];
      #pragma unroll
      for (int j=0;j<4;j++) acc[r][j] = MFMA(a, bb[j], acc[r][j]);
      int F = w*5 + r;
      if (F >= 32 && F < 36){               // Qs rows: add lo term
        int rowLo = F*16 - 512 + lr;
        bf16x8 alo = *(const bf16x8*)&LO[cur][rowLo*32 + swz];
        #pragma unroll
        for (int j=0;j<4;j++) acc[r][j] = MFMA(alo, bb[j], acc[r][j]);
      }
    }
  }

  int rq = (lane>>4)<<2;
  // ---- gate pair-reduce over QK frags (F<32) ----
  {
    float p[4] = {0.f,0.f,0.f,0.f};
    #pragma unroll
    for (int r=0;r<5;r++){
      int F = w*5 + r;
      if (F < 32){
        f32x4 bg = *(const f32x4*)&BG[F*16 + rq];
        #pragma unroll
        for (int j=0;j<4;j++){
          f32x4 a4 = acc[r][j];
          p[j] += (a4[0]+bg[0])*(a4[1]+bg[1]) + (a4[2]+bg[2])*(a4[3]+bg[3]);
        }
      }
    }
    #pragma unroll
    for (int j=0;j<4;j++){ p[j] += __shfl_xor(p[j],16); p[j] += __shfl_xor(p[j],32); }
    if (lane < 16){
      #pragma unroll
      for (int j=0;j<4;j++) QKf[w*64 + j*16 + lane] = p[j];
    }
  }
  __syncthreads();
  if (tid < 64){
    float s = 0.f;
    #pragma unroll
    for (int ww=0;ww<8;ww++) s += QKf[ww*64 + tid];
    GF[tid] = 1.f/(1.f + __expf(-s*(1.f/256.f)));
  }
  __syncthreads();

  // ---- Qs (F 32-35) and Ke (F 36-39) epilogues ----
  #pragma unroll
  for (int r=0;r<5;r++){
    int F = w*5 + r;
    if (F >= 32 && F < 36){
      int row0 = F*16 - 512 + rq;
      f32x4 bs4 = *(const f32x4*)&BSE[row0];
      float srow[4] = {0.f,0.f,0.f,0.f};
      #pragma unroll
      for (int j=0;j<4;j++){
        int nl = j*16 + lr;
        float g = GF[nl];
        int n = n0 + nl;
        #pragma unroll
        for (int q=0;q<4;q++){
          float v = (acc[r][j][q] + bs4[q]) * g;
          QSG[((size_t)(b*64) + row0 + q)*NPIX + n] = v;
          srow[q] += v;
        }
      }
      #pragma unroll
      for (int q=0;q<4;q++){
        float v = srow[q];
        v += __shfl_xor(v,1); v += __shfl_xor(v,2);
        v += __shfl_xor(v,4); v += __shfl_xor(v,8);
        if (lr == 0) atomicAdd(&S[b*64 + row0 + q], v);
      }
    } else if (F >= 36){
      int d0 = F*16 - 576 + rq;
      f32x4 be4 = *(const f32x4*)&BSE[64 + d0];
      #pragma unroll
      for (int j=0;j<4;j++){
        int n = n0 + j*16 + lr;
        PK4 pk;
        #pragma unroll
        for (int q=0;q<4;q++) pk.s[q] = (short)bf16_rne(acc[r][j][q] + be4[q]);
        *(uint2*)&KET[((size_t)(b*NPIX) + n)*64 + d0] = pk.u;
      }
    }
  }
}

// ---------------- M[b][512][64] += x . QSG^T over n (reg-split, no LDS) ----------------
__global__ __launch_bounds__(512)
void k_M(const float* __restrict__ x, const float* __restrict__ QSG,
         float* __restrict__ M){
  int slab = blockIdx.x, b = blockIdx.y;   // 16 slabs x 256 n
  int tid = threadIdx.x, w = tid>>6, lane = tid&63;
  int lr = lane&15, lk8 = (lane>>4)<<3;
  f32x4 acc[4][4] = {};
  for (int kt=0; kt<8; kt++){
    int noff = slab*256 + kt*32 + lk8;
    bf16x8 bh[4], bl[4];
    #pragma unroll
    for (int j=0;j<4;j++){
      const float* qp = QSG + ((size_t)(b*64) + j*16 + lr)*NPIX + noff;
      split8(*(const float4*)qp, *(const float4*)(qp+4), bh[j], bl[j]);
    }
    #pragma unroll
    for (int r=0;r<4;r++){
      const float* xp = x + ((size_t)(b*CIN) + w*64 + r*16 + lr)*NPIX + noff;
      bf16x8 ah, al;
      split8(*(const float4*)xp, *(const float4*)(xp+4), ah, al);
      #pragma unroll
      for (int j=0;j<4;j++){
        acc[r][j] = MFMA(al, bh[j], acc[r][j]);
        acc[r][j] = MFMA(ah, bl[j], acc[r][j]);
        acc[r][j] = MFMA(ah, bh[j], acc[r][j]);
      }
    }
  }
  int rq = (lane>>4)<<2;
  #pragma unroll
  for (int r=0;r<4;r++)
    #pragma unroll
    for (int j=0;j<4;j++)
      #pragma unroll
      for (int q=0;q<4;q++)
        atomicAdd(&M[((size_t)(b*CIN) + w*64 + r*16 + rq + q)*64 + j*16 + lr], acc[r][j][q]);
}

// ---------------- energy = Wv(f32) . M + bv*S  (VALU, exact) ----------------
__global__ __launch_bounds__(256)
void k_energy(const float* __restrict__ Wv, const float* __restrict__ bv,
              const float* __restrict__ M, const float* __restrict__ S,
              float* __restrict__ EN){
  __shared__ __align__(16) float ML[128*68];
  int cch = blockIdx.x, b = blockIdx.y;
  int tid = threadIdx.x;
  int d4 = tid & 15, ci = tid >> 4;
  f32x4 acc[2] = {};
  for (int kt=0; kt<4; kt++){
    __syncthreads();
    for (int i = tid; i < 2048; i += 256){
      int k = i >> 4, c4 = (i & 15) * 4;
      *(float4*)&ML[k*68 + c4] = *(const float4*)&M[((size_t)(b*CIN) + kt*128 + k)*64 + c4];
    }
    __syncthreads();
    #pragma unroll
    for (int m=0;m<2;m++){
      int c = cch*32 + ci + 16*m;
      const float* wvp = Wv + (size_t)c*512 + kt*128;
      for (int k4=0;k4<32;k4++){
        float4 wv4 = *(const float4*)(wvp + k4*4);
        f32x4 m0 = *(const f32x4*)&ML[(k4*4+0)*68 + d4*4];
        f32x4 m1 = *(const f32x4*)&ML[(k4*4+1)*68 + d4*4];
        f32x4 m2 = *(const f32x4*)&ML[(k4*4+2)*68 + d4*4];
        f32x4 m3 = *(const f32x4*)&ML[(k4*4+3)*68 + d4*4];
        acc[m] += m0*wv4.x + m1*wv4.y + m2*wv4.z + m3*wv4.w;
      }
    }
  }
  f32x4 s4 = *(const f32x4*)&S[b*64 + d4*4];
  #pragma unroll
  for (int m=0;m<2;m++){
    int c = cch*32 + ci + 16*m;
    f32x4 r = acc[m] + s4*bv[c];
    *(f32x4*)&EN[((size_t)(b*CIN) + c)*64 + d4*4] = r;
  }
}

// ---------------- softmax over d=64 ----------------
__global__ __launch_bounds__(256)
void k_softmax(const float* __restrict__ EN, short* __restrict__ ATT){
  int row = blockIdx.x*4 + (threadIdx.x>>6);
  int lane = threadIdx.x & 63;
  float v = EN[(size_t)row*64 + lane];
  float m = v;
  #pragma unroll
  for (int s=1;s<64;s<<=1) m = fmaxf(m, __shfl_xor(m, s));
  float e = __expf(v - m);
  float sum = e;
  #pragma unroll
  for (int s=1;s<64;s<<=1) sum += __shfl_xor(sum, s);
  ATT[(size_t)row*64 + lane] = (short)bf16_rne(e / sum);
}

// ---------------- out = x + attn . Ke ----------------
__global__ __launch_bounds__(512)
void k_out(const float* __restrict__ x, const short* __restrict__ ATT,
           const short* __restrict__ KET, float* __restrict__ out){
  int nt = blockIdx.x, b = blockIdx.y;
  int n0 = nt*64;
  int tid = threadIdx.x, w = tid>>6, lane = tid&63;
  int lr = lane&15, lk = (lane>>4)<<3;
  f32x4 acc[4][4] = {};
  #pragma unroll
  for (int kt=0; kt<2; kt++){
    bf16x8 bb[4];
    #pragma unroll
    for (int j=0;j<4;j++)
      bb[j] = *(const bf16x8*)&KET[((size_t)(b*NPIX) + n0 + j*16 + lr)*64 + kt*32 + lk];
    #pragma unroll
    for (int r=0;r<4;r++){
      bf16x8 a = *(const bf16x8*)&ATT[((size_t)(b*CIN) + w*64 + r*16 + lr)*64 + kt*32 + lk];
      #pragma unroll
      for (int j=0;j<4;j++)
        acc[r][j] = MFMA(a, bb[j], acc[r][j]);
    }
  }
  int rq = (lane>>4)<<2;
  #pragma unroll
  for (int r=0;r<4;r++)
    #pragma unroll
    for (int j=0;j<4;j++){
      int col = n0 + j*16 + lr;
      #pragma unroll
      for (int q=0;q<4;q++){
        size_t idx = ((size_t)(b*CIN) + w*64 + r*16 + rq + q)*NPIX + col;
        out[idx] = x[idx] + acc[r][j][q];
      }
    }
}

extern "C" void kernel_launch(void* const* d_in, const int* in_sizes, int n_in,
                              void* d_out, int out_size, void* d_ws, size_t ws_size,
                              hipStream_t stream){
  const float* x   = (const float*)d_in[0];
  const float* Wq  = (const float*)d_in[1];
  const float* bq  = (const float*)d_in[2];
  const float* Wk  = (const float*)d_in[3];
  const float* bk  = (const float*)d_in[4];
  const float* Wv  = (const float*)d_in[5];
  const float* bv  = (const float*)d_in[6];
  const float* Wsq = (const float*)d_in[7];
  const float* bsq = (const float*)d_in[8];
  const float* We  = (const float*)d_in[9];
  const float* be  = (const float*)d_in[10];
  float* out = (float*)d_out;

  char* wsb = (char*)d_ws;
  size_t off = 0;
  auto alloc = [&](size_t bytes)->void*{
    void* p = wsb + off; off += (bytes + 255) & ~(size_t)255; return p;
  };
  short* WALL = (short*)alloc((size_t)640*512*2);
  short* WLOT = (short*)alloc((size_t)64*512*2);
  float* BG   = (float*)alloc(512*4);
  float* BSE  = (float*)alloc(128*4);
  float* QSG  = (float*)alloc((size_t)BATCH*64*NPIX*4);
  short* KET  = (short*)alloc((size_t)BATCH*NPIX*64*2);
  float* Mb   = (float*)alloc((size_t)BATCH*512*64*4);
  float* Sb   = (float*)alloc((size_t)BATCH*64*4);
  float* EN   = (float*)alloc((size_t)BATCH*512*64*4);
  short* ATT  = (short*)alloc((size_t)BATCH*512*64*2);

  hipMemsetAsync(Mb, 0, (size_t)BATCH*512*64*4, stream);
  hipMemsetAsync(Sb, 0, (size_t)BATCH*64*4, stream);

  k_convw  <<<1280, 256, 0, stream>>>(Wq,bq,Wk,bk,Wsq,bsq,We,be, WALL,WLOT,BG,BSE);
  k_front  <<<dim3(64,16), 512, 0, stream>>>(x, WALL, WLOT, BG, BSE, QSG, KET, Sb);
  k_M      <<<dim3(16,16), 512, 0, stream>>>(x, QSG, Mb);
  k_energy <<<dim3(16,16), 256, 0, stream>>>(Wv, bv, Mb, Sb, EN);
  k_softmax<<<2048, 256, 0, stream>>>(EN, ATT);
  k_out    <<<dim3(64,16), 512, 0, stream>>>(x, ATT, KET, out);
}

// Round 12
// 266.052 us; speedup vs baseline: 1.0481x; 1.0375x over previous
//
#include <hip/hip_runtime.h>

#define BATCH 16
#define CIN 512
#define NPIX 4096

typedef __attribute__((ext_vector_type(8))) short bf16x8;
typedef __attribute__((ext_vector_type(4))) float f32x4;

#define MFMA(a,b,c) __builtin_amdgcn_mfma_f32_16x16x32_bf16((a),(b),(c),0,0,0)

union PK  { short s[8]; bf16x8 v; };
union PK4 { short s[4]; uint2 u; };

__device__ __forceinline__ unsigned short bf16_rne(float f){
  unsigned u = __float_as_uint(f);
  return (unsigned short)((u + 0x7fffu + ((u >> 16) & 1u)) >> 16);
}
__device__ __forceinline__ void f32_split(float f, short &h, short &l){
  unsigned short hu = bf16_rne(f);
  h = (short)hu;
  float fh = __uint_as_float((unsigned)hu << 16);
  l = (short)bf16_rne(f - fh);
}
__device__ __forceinline__ void split8(float4 a, float4 b, bf16x8 &h, bf16x8 &l){
  float vv[8] = {a.x,a.y,a.z,a.w,b.x,b.y,b.z,b.w};
  PK ph, pl;
  #pragma unroll
  for (int z=0;z<8;z++){ short hh,ll; f32_split(vv[z],hh,ll); ph.s[z]=hh; pl.s[z]=ll; }
  h = ph.v; l = pl.v;
}

// chunk-XOR swizzle within a 512-short row: (row,k) -> row*512 + slot*8 + (k&7)
__device__ __forceinline__ int offBig(int row, int k){
  int s = k >> 3;
  s = (s & ~7) | ((s ^ row) & 7);
  return row*512 + s*8 + (k & 7);
}

// ---------------- weight convert ----------------
// WALL [16 kt][640 rows][32 k] bf16, K-step-major, chunk^row&3 swizzle baked in.
//   rows 0-511: interleaved gate (2o=Wq[o], 2o+1=Wk[o]); 512-575: Ws hi; 576-639: We hi.
// WLOT [16 kt][64 rows][32 k]: Ws lo, same swizzle.
__global__ __launch_bounds__(256)
void k_convw(const float* __restrict__ Wq, const float* __restrict__ bq,
             const float* __restrict__ Wk, const float* __restrict__ bk,
             const float* __restrict__ Ws, const float* __restrict__ bs,
             const float* __restrict__ We, const float* __restrict__ be,
             short* __restrict__ WALL, short* __restrict__ WLOT,
             float* __restrict__ BG, float* __restrict__ BSE){
  int t = blockIdx.x*256 + threadIdx.x;   // t < 640*512
  if (t < 640*512){
    int r = t >> 9, k = t & 511;
    float v = (r < 512) ? ((r & 1) ? Wk[(r>>1)*512 + k] : Wq[(r>>1)*512 + k])
            : (r < 576) ? Ws[(r-512)*512 + k] : We[(r-576)*512 + k];
    short h, l; f32_split(v, h, l);
    int kt = k >> 5, lc = (k >> 3) & 3, e = k & 7;
    int pc = lc ^ (r & 3);
    WALL[((size_t)kt*640 + r)*32 + pc*8 + e] = h;
    if (r >= 512 && r < 576){
      int rlo = r - 512;
      WLOT[((size_t)kt*64 + rlo)*32 + (lc ^ (rlo & 3))*8 + e] = l;
    }
  }
  if (t < 512) BG[t] = (t & 1) ? bk[t>>1] : bq[t>>1];
  if (t < 128) BSE[t] = (t < 64) ? bs[t] : be[t-64];
}

// ---------------- fused front: gate + Qs(split,gate-folded) + Ke ----------------
// n-tile 128 (512 blocks): HALVES total weight-byte traffic (the measured wall:
// ~22 GB/s/CU L2 inbound). Whole-tile XS[128][512] (128 KB), ONE barrier total,
// no DMA, no dbuf: each wave streams WALL fragments independently; acc 160 VGPR.
__global__ __launch_bounds__(512, 2)
void k_front(const float* __restrict__ x, const short* __restrict__ WALL,
             const short* __restrict__ WLOT, const float* __restrict__ BG,
             const float* __restrict__ BSE,
             float* __restrict__ QSG, short* __restrict__ KET, float* __restrict__ S){
  __shared__ __align__(16) short XS[128*512];     // 128 KB, [n][c] swizzled
  __shared__ float QKf[8*128];                    // 4 KB
  __shared__ float GF[128];
  int nt = blockIdx.x, b = blockIdx.y;
  int n0 = nt*128;
  int tid = threadIdx.x, w = tid>>6, lane = tid&63;
  int lr = lane&15, lk = (lane>>4)<<3;
  int cg = lane>>4;                               // k-chunk 0..3

  // XS stage, coalesced: 4 lanes per channel row, 8 float4 each (128 n)
  {
    int c0 = tid >> 2;               // 0..127
    int ni = (tid & 3) * 4;          // float offset
    #pragma unroll
    for (int p=0;p<4;p++){
      int cc = p*128 + c0;
      const float* xp = x + ((size_t)b*CIN + cc)*NPIX + n0 + ni;
      float4 vv[8];
      #pragma unroll
      for (int u=0;u<8;u++) vv[u] = *(const float4*)(xp + u*16);
      #pragma unroll
      for (int u=0;u<8;u++){
        float f[4] = {vv[u].x, vv[u].y, vv[u].z, vv[u].w};
        #pragma unroll
        for (int z=0;z<4;z++)
          XS[offBig(ni + u*16 + z, cc)] = (short)bf16_rne(f[z]);
      }
    }
  }
  __syncthreads();                                // the ONLY barrier before epilogue

  f32x4 acc[5][8] = {};
  int rowBase = w*80;                             // 5 frags x 16 rows per wave
  int swz = ((cg ^ (lr & 3)) << 3);

  for (int kt=0; kt<16; kt++){
    bf16x8 bb[8];
    #pragma unroll
    for (int j=0;j<8;j++)
      bb[j] = *(const bf16x8*)&XS[offBig(j*16+lr, kt*32+lk)];
    const short* wk = WALL + (size_t)kt*640*32;
    #pragma unroll
    for (int r=0;r<5;r++){
      int rowL = rowBase + r*16 + lr;
      bf16x8 a = *(const bf16x8*)&wk[rowL*32 + swz];
      #pragma unroll
      for (int j=0;j<8;j++) acc[r][j] = MFMA(a, bb[j], acc[r][j]);
      int F = w*5 + r;
      if (F >= 32 && F < 36){                     // Qs rows: add lo term
        bf16x8 alo = *(const bf16x8*)&WLOT[(size_t)kt*64*32 + (F*16-512+lr)*32 + swz];
        #pragma unroll
        for (int j=0;j<8;j++) acc[r][j] = MFMA(alo, bb[j], acc[r][j]);
      }
    }
  }

  int rq = (lane>>4)<<2;
  // ---- gate pair-reduce over QK frags (F<32) ----
  {
    float p[8] = {0.f,0.f,0.f,0.f,0.f,0.f,0.f,0.f};
    #pragma unroll
    for (int r=0;r<5;r++){
      int F = w*5 + r;
      if (F < 32){
        f32x4 bg = *(const f32x4*)&BG[F*16 + rq];
        #pragma unroll
        for (int j=0;j<8;j++){
          f32x4 a4 = acc[r][j];
          p[j] += (a4[0]+bg[0])*(a4[1]+bg[1]) + (a4[2]+bg[2])*(a4[3]+bg[3]);
        }
      }
    }
    #pragma unroll
    for (int j=0;j<8;j++){ p[j] += __shfl_xor(p[j],16); p[j] += __shfl_xor(p[j],32); }
    if (lane < 16){
      #pragma unroll
      for (int j=0;j<8;j++) QKf[w*128 + j*16 + lane] = p[j];
    }
  }
  __syncthreads();
  if (tid < 128){
    float s = 0.f;
    #pragma unroll
    for (int ww=0;ww<8;ww++) s += QKf[ww*128 + tid];
    GF[tid] = 1.f/(1.f + __expf(-s*(1.f/256.f)));
  }
  __syncthreads();

  // ---- Qs (F 32-35) and Ke (F 36-39) epilogues ----
  #pragma unroll
  for (int r=0;r<5;r++){
    int F = w*5 + r;
    if (F >= 32 && F < 36){
      int row0 = F*16 - 512 + rq;
      f32x4 bs4 = *(const f32x4*)&BSE[row0];
      float srow[4] = {0.f,0.f,0.f,0.f};
      #pragma unroll
      for (int j=0;j<8;j++){
        int nl = j*16 + lr;
        float g = GF[nl];
        int n = n0 + nl;
        #pragma unroll
        for (int q=0;q<4;q++){
          float v = (acc[r][j][q] + bs4[q]) * g;
          QSG[((size_t)(b*64) + row0 + q)*NPIX + n] = v;
          srow[q] += v;
        }
      }
      #pragma unroll
      for (int q=0;q<4;q++){
        float v = srow[q];
        v += __shfl_xor(v,1); v += __shfl_xor(v,2);
        v += __shfl_xor(v,4); v += __shfl_xor(v,8);
        if (lr == 0) atomicAdd(&S[b*64 + row0 + q], v);
      }
    } else if (F >= 36){
      int d0 = F*16 - 576 + rq;
      f32x4 be4 = *(const f32x4*)&BSE[64 + d0];
      #pragma unroll
      for (int j=0;j<8;j++){
        int n = n0 + j*16 + lr;
        PK4 pk;
        #pragma unroll
        for (int q=0;q<4;q++) pk.s[q] = (short)bf16_rne(acc[r][j][q] + be4[q]);
        *(uint2*)&KET[((size_t)(b*NPIX) + n)*64 + d0] = pk.u;
      }
    }
  }
}

// ---------------- M[b][512][64] += x . QSG^T over n (reg-split, no LDS) ----------------
__global__ __launch_bounds__(512)
void k_M(const float* __restrict__ x, const float* __restrict__ QSG,
         float* __restrict__ M){
  int slab = blockIdx.x, b = blockIdx.y;   // 16 slabs x 256 n
  int tid = threadIdx.x, w = tid>>6, lane = tid&63;
  int lr = lane&15, lk8 = (lane>>4)<<3;
  f32x4 acc[4][4] = {};
  for (int kt=0; kt<8; kt++){
    int noff = slab*256 + kt*32 + lk8;
    bf16x8 bh[4], bl[4];
    #pragma unroll
    for (int j=0;j<4;j++){
      const float* qp = QSG + ((size_t)(b*64) + j*16 + lr)*NPIX + noff;
      split8(*(const float4*)qp, *(const float4*)(qp+4), bh[j], bl[j]);
    }
    #pragma unroll
    for (int r=0;r<4;r++){
      const float* xp = x + ((size_t)(b*CIN) + w*64 + r*16 + lr)*NPIX + noff;
      bf16x8 ah, al;
      split8(*(const float4*)xp, *(const float4*)(xp+4), ah, al);
      #pragma unroll
      for (int j=0;j<4;j++){
        acc[r][j] = MFMA(al, bh[j], acc[r][j]);
        acc[r][j] = MFMA(ah, bl[j], acc[r][j]);
        acc[r][j] = MFMA(ah, bh[j], acc[r][j]);
      }
    }
  }
  int rq = (lane>>4)<<2;
  #pragma unroll
  for (int r=0;r<4;r++)
    #pragma unroll
    for (int j=0;j<4;j++)
      #pragma unroll
      for (int q=0;q<4;q++)
        atomicAdd(&M[((size_t)(b*CIN) + w*64 + r*16 + rq + q)*64 + j*16 + lr], acc[r][j][q]);
}

// ---------------- energy = Wv(f32) . M + bv*S  (VALU, exact) ----------------
__global__ __launch_bounds__(256)
void k_energy(const float* __restrict__ Wv, const float* __restrict__ bv,
              const float* __restrict__ M, const float* __restrict__ S,
              float* __restrict__ EN){
  __shared__ __align__(16) float ML[128*68];
  int cch = blockIdx.x, b = blockIdx.y;
  int tid = threadIdx.x;
  int d4 = tid & 15, ci = tid >> 4;
  f32x4 acc[2] = {};
  for (int kt=0; kt<4; kt++){
    __syncthreads();
    for (int i = tid; i < 2048; i += 256){
      int k = i >> 4, c4 = (i & 15) * 4;
      *(float4*)&ML[k*68 + c4] = *(const float4*)&M[((size_t)(b*CIN) + kt*128 + k)*64 + c4];
    }
    __syncthreads();
    #pragma unroll
    for (int m=0;m<2;m++){
      int c = cch*32 + ci + 16*m;
      const float* wvp = Wv + (size_t)c*512 + kt*128;
      for (int k4=0;k4<32;k4++){
        float4 wv4 = *(const float4*)(wvp + k4*4);
        f32x4 m0 = *(const f32x4*)&ML[(k4*4+0)*68 + d4*4];
        f32x4 m1 = *(const f32x4*)&ML[(k4*4+1)*68 + d4*4];
        f32x4 m2 = *(const f32x4*)&ML[(k4*4+2)*68 + d4*4];
        f32x4 m3 = *(const f32x4*)&ML[(k4*4+3)*68 + d4*4];
        acc[m] += m0*wv4.x + m1*wv4.y + m2*wv4.z + m3*wv4.w;
      }
    }
  }
  f32x4 s4 = *(const f32x4*)&S[b*64 + d4*4];
  #pragma unroll
  for (int m=0;m<2;m++){
    int c = cch*32 + ci + 16*m;
    f32x4 r = acc[m] + s4*bv[c];
    *(f32x4*)&EN[((size_t)(b*CIN) + c)*64 + d4*4] = r;
  }
}

// ---------------- softmax over d=64 ----------------
__global__ __launch_bounds__(256)
void k_softmax(const float* __restrict__ EN, short* __restrict__ ATT){
  int row = blockIdx.x*4 + (threadIdx.x>>6);
  int lane = threadIdx.x & 63;
  float v = EN[(size_t)row*64 + lane];
  float m = v;
  #pragma unroll
  for (int s=1;s<64;s<<=1) m = fmaxf(m, __shfl_xor(m, s));
  float e = __expf(v - m);
  float sum = e;
  #pragma unroll
  for (int s=1;s<64;s<<=1) sum += __shfl_xor(sum, s);
  ATT[(size_t)row*64 + lane] = (short)bf16_rne(e / sum);
}

// ---------------- out = x + attn . Ke ----------------
__global__ __launch_bounds__(512)
void k_out(const float* __restrict__ x, const short* __restrict__ ATT,
           const short* __restrict__ KET, float* __restrict__ out){
  int nt = blockIdx.x, b = blockIdx.y;
  int n0 = nt*64;
  int tid = threadIdx.x, w = tid>>6, lane = tid&63;
  int lr = lane&15, lk = (lane>>4)<<3;
  f32x4 acc[4][4] = {};
  #pragma unroll
  for (int kt=0; kt<2; kt++){
    bf16x8 bb[4];
    #pragma unroll
    for (int j=0;j<4;j++)
      bb[j] = *(const bf16x8*)&KET[((size_t)(b*NPIX) + n0 + j*16 + lr)*64 + kt*32 + lk];
    #pragma unroll
    for (int r=0;r<4;r++){
      bf16x8 a = *(const bf16x8*)&ATT[((size_t)(b*CIN) + w*64 + r*16 + lr)*64 + kt*32 + lk];
      #pragma unroll
      for (int j=0;j<4;j++)
        acc[r][j] = MFMA(a, bb[j], acc[r][j]);
    }
  }
  int rq = (lane>>4)<<2;
  #pragma unroll
  for (int r=0;r<4;r++)
    #pragma unroll
    for (int j=0;j<4;j++){
      int col = n0 + j*16 + lr;
      #pragma unroll
      for (int q=0;q<4;q++){
        size_t idx = ((size_t)(b*CIN) + w*64 + r*16 + rq + q)*NPIX + col;
        out[idx] = x[idx] + acc[r][j][q];
      }
    }
}

extern "C" void kernel_launch(void* const* d_in, const int* in_sizes, int n_in,
                              void* d_out, int out_size, void* d_ws, size_t ws_size,
                              hipStream_t stream){
  const float* x   = (const float*)d_in[0];
  const float* Wq  = (const float*)d_in[1];
  const float* bq  = (const float*)d_in[2];
  const float* Wk  = (const float*)d_in[3];
  const float* bk  = (const float*)d_in[4];
  const float* Wv  = (const float*)d_in[5];
  const float* bv  = (const float*)d_in[6];
  const float* Wsq = (const float*)d_in[7];
  const float* bsq = (const float*)d_in[8];
  const float* We  = (const float*)d_in[9];
  const float* be  = (const float*)d_in[10];
  float* out = (float*)d_out;

  char* wsb = (char*)d_ws;
  size_t off = 0;
  auto alloc = [&](size_t bytes)->void*{
    void* p = wsb + off; off += (bytes + 255) & ~(size_t)255; return p;
  };
  short* WALL = (short*)alloc((size_t)640*512*2);
  short* WLOT = (short*)alloc((size_t)64*512*2);
  float* BG   = (float*)alloc(512*4);
  float* BSE  = (float*)alloc(128*4);
  float* QSG  = (float*)alloc((size_t)BATCH*64*NPIX*4);
  short* KET  = (short*)alloc((size_t)BATCH*NPIX*64*2);
  float* Mb   = (float*)alloc((size_t)BATCH*512*64*4);
  float* Sb   = (float*)alloc((size_t)BATCH*64*4);
  float* EN   = (float*)alloc((size_t)BATCH*512*64*4);
  short* ATT  = (short*)alloc((size_t)BATCH*512*64*2);

  hipMemsetAsync(Mb, 0, (size_t)BATCH*512*64*4, stream);
  hipMemsetAsync(Sb, 0, (size_t)BATCH*64*4, stream);

  k_convw  <<<1280, 256, 0, stream>>>(Wq,bq,Wk,bk,Wsq,bsq,We,be, WALL,WLOT,BG,BSE);
  k_front  <<<dim3(32,16), 512, 0, stream>>>(x, WALL, WLOT, BG, BSE, QSG, KET, Sb);
  k_M      <<<dim3(16,16), 512, 0, stream>>>(x, QSG, Mb);
  k_energy <<<dim3(16,16), 256, 0, stream>>>(Wv, bv, Mb, Sb, EN);
  k_softmax<<<2048, 256, 0, stream>>>(EN, ATT);
  k_out    <<<dim3(64,16), 512, 0, stream>>>(x, ATT, KET, out);
}